// Round 4
// baseline (2485.586 us; speedup 1.0000x reference)
//
#include <hip/hip_runtime.h>

// LSTM (B=512, T=1024, I=64, H=128) + FC(128->256->1), fp32 in/out.
// Latency-optimal MFMA structure: 32 blocks x 1024 threads (1 block/CU,
// 4 waves/SIMD). Each block owns 16 batch rows (full N=16 MFMA columns) and
// all 512 gate rows. Wave w owns M-tiles {w, w+16}; stationary f16 weight
// fragments in VGPRs (80), B-fragments ([x_t | h] in f16) from LDS.
// Precision: 2-term f16 split. x-part: Whi*(xhi+xlo) (x exact to 2^-22,
// W to 2^-11). h-part: (Whi+Wlo)*h16 (W exact to 2^-22, h to 2^-12).
// Predicted absmax ~1e-3 vs threshold 3.1e-3 (anchored on round-2 meas.).

#define T_STEPS 1024
#define ISZ 64
#define HSZ 128
#define NB 16          // batch rows per block
#define NTH 1024
#define VSTR 200       // vhi row stride in f16 (pad: conflict-free, 16B-aligned)
#define XSTR 72        // vxlo row stride in f16
#define GSTR 516       // gbuf row stride in f32

typedef _Float16 f16x8 __attribute__((ext_vector_type(8)));
typedef float    f32x4 __attribute__((ext_vector_type(4)));

__device__ __forceinline__ float fast_sigmoid(float x) {
    return 1.0f / (1.0f + __expf(-x));
}
__device__ __forceinline__ float fast_tanh(float x) {
    float xc = fminf(fmaxf(x, -15.0f), 15.0f);
    float u = __expf(2.0f * xc);
    return (u - 1.0f) / (u + 1.0f);
}

__global__ __launch_bounds__(NTH, 4)   // hard 128-VGPR cap: block needs 4 waves/SIMD
void lstm_f16_kernel(const float* __restrict__ x,
                     const float* __restrict__ W_ih,
                     const float* __restrict__ W_hh,
                     const float* __restrict__ b_ih,
                     const float* __restrict__ b_hh,
                     const float* __restrict__ W1,
                     const float* __restrict__ b1,
                     const float* __restrict__ W2,
                     const float* __restrict__ b2,
                     float* __restrict__ out)
{
    __shared__ __align__(16) _Float16 vhi[NB][VSTR];   // k 0..63: x hi, 64..191: h16
    __shared__ __align__(16) _Float16 vxlo[NB][XSTR];  // k 0..63: x lo
    __shared__ __align__(16) float    gbuf[NB][GSTR];  // activated gates, batch-major
    __shared__ __align__(16) float    biasC[512];
    __shared__ __align__(16) float    hbuf[NB][HSZ];   // fp32 h at final step

    const int tid  = threadIdx.x;
    const int lane = tid & 63;
    const int w    = tid >> 6;       // wave 0..15
    const int n    = lane & 15;      // batch col (B/D) == A row-within-tile
    const int quad = lane >> 4;      // 0..3
    const int b0   = blockIdx.x * NB;

    const int m1 = 16 * w;           // tile1 rows [m1,m1+16): i/f gates -> sigmoid
    const int m2 = 256 + 16 * w;     // tile2: g (w<8, tanh) / o (w>=8, sigmoid)

    // ---- one-time: load + split weights into stationary f16 A-frags ----
    f16x8 whi[2][6];
    f16x8 wlo[2][4];   // h-part only (ks 2..5)
    #pragma unroll
    for (int tau = 0; tau < 2; ++tau) {
        const int g = (tau ? m2 : m1) + n;
        #pragma unroll
        for (int ks = 0; ks < 6; ++ks) {
            #pragma unroll
            for (int j = 0; j < 8; ++j) {
                const int k = ks * 32 + quad * 8 + j;
                float val = (k < ISZ) ? W_ih[(size_t)g * ISZ + k]
                                      : W_hh[(size_t)g * HSZ + (k - ISZ)];
                _Float16 hi = (_Float16)val;
                whi[tau][ks][j] = hi;
                if (ks >= 2) wlo[tau][ks - 2][j] = (_Float16)(val - (float)hi);
            }
        }
    }

    // ---- init LDS: bias, zero h-region, stage x(t=0) ----
    if (tid < 512) biasC[tid] = b_ih[tid] + b_hh[tid];
    {   // zero vhi h-region: 16 rows x 128 = 2048 f16, 2 per thread
        const int rb = tid >> 6, jj = tid & 63;
        vhi[rb][ISZ + jj]      = (_Float16)0.0f;
        vhi[rb][ISZ + 64 + jj] = (_Float16)0.0f;
    }
    {   // x(t=0): thread (row w, col lane)
        float xv = x[((size_t)(b0 + w) * T_STEPS + 0) * ISZ + lane];
        _Float16 hi = (_Float16)xv;
        vhi[w][lane]  = hi;
        vxlo[w][lane] = (_Float16)(xv - (float)hi);
    }
    // cell state: thread owns (b=tid>>7, j=tid&127) and (b+8, j)
    float cA = 0.0f, cB = 0.0f;
    const int hb = tid >> 7;         // 0..7
    const int hj = tid & 127;
    __syncthreads();

    const _Float16* vbase = &vhi[n][quad * 8];
    const _Float16* xlbase = &vxlo[n][quad * 8];
    const int tanh_sel = (w < 8);    // wave-uniform

    #pragma unroll 1
    for (int t = 0; t < T_STEPS; ++t) {
        // x(t+1) prefetch (global; consumed in phase C)
        float xn = 0.0f;
        const bool pf = (t + 1 < T_STEPS);
        if (pf)
            xn = x[((size_t)(b0 + w) * T_STEPS + (t + 1)) * ISZ + lane];

        // ---- MFMA phase ----
        f32x4 acc1 = *(const f32x4*)&biasC[m1 + quad * 4];
        f32x4 acc2 = *(const f32x4*)&biasC[m2 + quad * 4];
        #pragma unroll
        for (int ks = 0; ks < 2; ++ks) {   // x-part: Whi*(xhi + xlo)
            f16x8 bxh = *(const f16x8*)(vbase + ks * 32);
            f16x8 bxl = *(const f16x8*)(xlbase + ks * 32);
            acc1 = __builtin_amdgcn_mfma_f32_16x16x32_f16(whi[0][ks], bxh, acc1, 0, 0, 0);
            acc2 = __builtin_amdgcn_mfma_f32_16x16x32_f16(whi[1][ks], bxh, acc2, 0, 0, 0);
            acc1 = __builtin_amdgcn_mfma_f32_16x16x32_f16(whi[0][ks], bxl, acc1, 0, 0, 0);
            acc2 = __builtin_amdgcn_mfma_f32_16x16x32_f16(whi[1][ks], bxl, acc2, 0, 0, 0);
        }
        #pragma unroll
        for (int ks = 2; ks < 6; ++ks) {   // h-part: (Whi + Wlo)*h16
            f16x8 bh = *(const f16x8*)(vbase + ks * 32);
            acc1 = __builtin_amdgcn_mfma_f32_16x16x32_f16(whi[0][ks], bh, acc1, 0, 0, 0);
            acc2 = __builtin_amdgcn_mfma_f32_16x16x32_f16(whi[1][ks], bh, acc2, 0, 0, 0);
            acc1 = __builtin_amdgcn_mfma_f32_16x16x32_f16(wlo[0][ks - 2], bh, acc1, 0, 0, 0);
            acc2 = __builtin_amdgcn_mfma_f32_16x16x32_f16(wlo[1][ks - 2], bh, acc2, 0, 0, 0);
        }

        // ---- epilogue: activate, write gates (D: col=lane&15, row=quad*4+r) ----
        {
            f32x4 g1, g2;
            #pragma unroll
            for (int r = 0; r < 4; ++r) g1[r] = fast_sigmoid(acc1[r]);  // i/f
            #pragma unroll
            for (int r = 0; r < 4; ++r)
                g2[r] = tanh_sel ? fast_tanh(acc2[r]) : fast_sigmoid(acc2[r]);  // g / o
            *(f32x4*)&gbuf[n][m1 + quad * 4] = g1;
            *(f32x4*)&gbuf[n][m2 + quad * 4] = g2;
        }
        __syncthreads();   // A: gates ready; all v-reads of this step done

        // ---- phase C: c/h update (2 per thread) + x(t+1) store ----
        {
            float ig = gbuf[hb][hj];
            float fg = gbuf[hb][HSZ + hj];
            float gg = gbuf[hb][2 * HSZ + hj];
            float og = gbuf[hb][3 * HSZ + hj];
            cA = fmaf(fg, cA, ig * gg);
            float h = og * fast_tanh(cA);
            vhi[hb][ISZ + hj] = (_Float16)h;
            if (t == T_STEPS - 1) hbuf[hb][hj] = h;
        }
        {
            float ig = gbuf[hb + 8][hj];
            float fg = gbuf[hb + 8][HSZ + hj];
            float gg = gbuf[hb + 8][2 * HSZ + hj];
            float og = gbuf[hb + 8][3 * HSZ + hj];
            cB = fmaf(fg, cB, ig * gg);
            float h = og * fast_tanh(cB);
            vhi[hb + 8][ISZ + hj] = (_Float16)h;
            if (t == T_STEPS - 1) hbuf[hb + 8][hj] = h;
        }
        if (pf) {
            _Float16 hi = (_Float16)xn;
            vhi[w][lane]  = hi;
            vxlo[w][lane] = (_Float16)(xn - (float)hi);
        }
        __syncthreads();   // B: v ready for step t+1
    }

    // ---- FC head: wave w computes out[b0+w] ----
    {
        float z = 0.0f;
        #pragma unroll
        for (int s = 0; s < 4; ++s) {
            const int m = lane + 64 * s;
            const float4* w1r = reinterpret_cast<const float4*>(W1 + (size_t)m * HSZ);
            const float4* hr  = reinterpret_cast<const float4*>(hbuf[w]);
            float dot = 0.0f;
            #pragma unroll
            for (int k = 0; k < HSZ / 4; ++k) {
                float4 wv = w1r[k];
                float4 hv = hr[k];
                dot = fmaf(wv.x, hv.x, dot);
                dot = fmaf(wv.y, hv.y, dot);
                dot = fmaf(wv.z, hv.z, dot);
                dot = fmaf(wv.w, hv.w, dot);
            }
            z = fmaf(W2[m], dot + b1[m], z);
        }
        #pragma unroll
        for (int off = 32; off >= 1; off >>= 1)
            z += __shfl_down(z, off, 64);
        if (lane == 0) out[b0 + w] = z + b2[0];
    }
}

extern "C" void kernel_launch(void* const* d_in, const int* in_sizes, int n_in,
                              void* d_out, int out_size, void* d_ws, size_t ws_size,
                              hipStream_t stream) {
    const float* x    = (const float*)d_in[0];
    const float* W_ih = (const float*)d_in[1];
    const float* W_hh = (const float*)d_in[2];
    const float* b_ih = (const float*)d_in[3];
    const float* b_hh = (const float*)d_in[4];
    const float* W1   = (const float*)d_in[5];
    const float* b1   = (const float*)d_in[6];
    const float* W2   = (const float*)d_in[7];
    const float* b2   = (const float*)d_in[8];
    float* out = (float*)d_out;

    lstm_f16_kernel<<<dim3(512 / NB), dim3(NTH), 0, stream>>>(
        x, W_ih, W_hh, b_ih, b_hh, W1, b1, W2, b2, out);
}